// Round 3
// baseline (342.838 us; speedup 1.0000x reference)
//
#include <hip/hip_runtime.h>

#define NT      250000
#define NN      20000
#define RP      8
#define EMB     64
#define NCLS    16
#define NRELS   64
#define GROWS   128   // rows per block in k_gemv

// ---------------- A: LDS-staged per-pair GEMV + softmax + colsum scatter ----------------
// loads rm coalesced -> LDS (stride 65: 2-way banks = free), computes per-thread row,
// writes l1/l2 TRANSPOSED (coalesced stores, broadcast-friendly reads downstream)
__global__ __launch_bounds__(128) void k_gemv(
    const float* __restrict__ rm,
    const float* __restrict__ W1, const float* __restrict__ b1,
    const float* __restrict__ W2, const float* __restrict__ b2,
    const int* __restrict__ vcol,
    float* __restrict__ l1T, float* __restrict__ l2T,
    float* __restrict__ colsum)
{
    __shared__ float tile[GROWS * 65];
    __shared__ float w1s[NRELS * RP], w2s[NRELS * RP];
    __shared__ float red[GROWS];
    int t = threadIdx.x;
    for (int i = t; i < NRELS * RP; i += GROWS) { w1s[i] = W1[i]; w2s[i] = W2[i]; }

    int base = blockIdx.x * GROWS;
    const float4* src = reinterpret_cast<const float4*>(rm) + (size_t)base * 16;
    int limit = (NT - base) * 16;   // valid float4 count for this block
#pragma unroll
    for (int i = 0; i < 16; ++i) {
        int idx = i * GROWS + t;
        if (idx < limit) {
            float4 v = src[idx];
            float* d = &tile[(idx >> 4) * 65 + (idx & 15) * 4];
            d[0] = v.x; d[1] = v.y; d[2] = v.z; d[3] = v.w;
        }
    }
    __syncthreads();

    int p = base + t;
    float c0 = 0.f;
    if (p < NT) {
        float a1[RP], a2[RP];
#pragma unroll
        for (int r = 0; r < RP; ++r) { a1[r] = b1[r]; a2[r] = b2[r]; }
        const float* row = &tile[t * 65];
#pragma unroll 8
        for (int k = 0; k < NRELS; ++k) {
            float x = row[k];
#pragma unroll
            for (int r = 0; r < RP; ++r) {
                a1[r] = fmaf(x, w1s[k * RP + r], a1[r]);
                a2[r] = fmaf(x, w2s[k * RP + r], a2[r]);
            }
        }
        float m = a2[0];
#pragma unroll
        for (int r = 1; r < RP; ++r) m = fmaxf(m, a2[r]);
        float s = 0.f;
#pragma unroll
        for (int r = 0; r < RP; ++r) { a2[r] = __expf(a2[r] - m); s += a2[r]; }
        float inv = 1.0f / s;
#pragma unroll
        for (int r = 0; r < RP; ++r) a2[r] *= inv;

        c0 = a1[0];
        int o = vcol[p];
#pragma unroll
        for (int r = 1; r < RP; ++r) atomicAdd(&colsum[o * r], a1[r]);
#pragma unroll
        for (int r = 0; r < RP; ++r) {
            l1T[(size_t)r * NT + p] = a1[r];
            l2T[(size_t)r * NT + p] = a2[r];
        }
    }
    // block-reduce r==0 contributions -> colsum[0]
    red[t] = c0;
    __syncthreads();
    for (int off = GROWS / 2; off > 0; off >>= 1) {
        if (t < off) red[t] += red[t + off];
        __syncthreads();
    }
    if (t == 0) atomicAdd(&colsum[0], red[0]);
}

// ---------------- CSR offsets: hrow[0:NT] is sorted (np.unique axis=0) ----------------
__global__ __launch_bounds__(256) void k_rowptr(
    const int* __restrict__ hrow, int* __restrict__ rowptr)
{
    int i = blockIdx.x * blockDim.x + threadIdx.x;
    if (i > NN) return;
    int lo = 0, hi = NT;
    while (lo < hi) { int mid = (lo + hi) >> 1; if (hrow[mid] < i) lo = mid + 1; else hi = mid; }
    rowptr[i] = lo;
}

// ---------------- C: one wave per node s, no atomics ----------------
__global__ __launch_bounds__(256) void k_h(
    const float* __restrict__ l1T, const float* __restrict__ colsum,
    const int* __restrict__ rowptr, const int* __restrict__ vcol,
    const float* __restrict__ w1, const float* __restrict__ bias1,
    float* __restrict__ h)
{
    int wave = (int)((blockIdx.x * blockDim.x + threadIdx.x) >> 6);
    int lane = threadIdx.x & 63;
    if (wave >= NN) return;
    int s = wave;
    int pb = rowptr[s], pe = rowptr[s + 1];
    float acc = 0.f;
    float c0 = 0.f;                      // r==0 factored: seg 0, same w1 row
    for (int p = pb; p < pe; ++p) {
        int o = vcol[p];
        c0 += l1T[p];
#pragma unroll
        for (int r = 1; r < RP; ++r) {
            int seg = o * r;
            float coef = l1T[(size_t)r * NT + p] / colsum[seg];
            acc = fmaf(coef, w1[(size_t)seg * EMB + lane], acc);
        }
    }
    acc = fmaf(c0 / colsum[0], w1[lane], acc);
    h[(size_t)s * EMB + lane] = fmaxf(acc + bias1[lane], 0.f);
}

// ---------------- D: one wave per node s; register-resident 8x64 block ----------------
__global__ __launch_bounds__(256) void k_h2(
    const float* __restrict__ l2T, const int* __restrict__ rowptr,
    const int* __restrict__ vcol, const float* __restrict__ h,
    float* __restrict__ h2raw, float* __restrict__ rowsum,
    float* __restrict__ Abuf0, float* __restrict__ rs0part)
{
    int wave = (int)((blockIdx.x * blockDim.x + threadIdx.x) >> 6);
    int lane = threadIdx.x & 63;
    if (wave >= NN) return;
    int s = wave;
    int pb = rowptr[s], pe = rowptr[s + 1];
    float acc[RP], rs[RP];
#pragma unroll
    for (int r = 0; r < RP; ++r) { acc[r] = 0.f; rs[r] = 0.f; }
    for (int p = pb; p < pe; ++p) {
        int o = vcol[p];
        float hv = h[(size_t)o * EMB + lane];
#pragma unroll
        for (int r = 0; r < RP; ++r) {
            float lv = l2T[(size_t)r * NT + p];
            acc[r] = fmaf(lv, hv, acc[r]);
            rs[r] += lv;
        }
    }
    if (s == 0) {
        float a0 = 0.f, r0 = 0.f;
#pragma unroll
        for (int r = 0; r < RP; ++r) { a0 += acc[r]; r0 += rs[r]; }
        Abuf0[lane] = a0;
        if (lane == 0) rs0part[0] = r0;
    } else {
        Abuf0[(size_t)s * EMB + lane] = acc[0];
        if (lane == 0) rs0part[s] = rs[0];
#pragma unroll
        for (int r = 1; r < RP; ++r) {
            int seg = s * r;
            atomicAdd(&h2raw[(size_t)seg * EMB + lane], acc[r]);
            if (lane == 0) atomicAdd(&rowsum[seg], rs[r]);
        }
    }
}

// ---------------- reduce seg-0 partials ----------------
__global__ __launch_bounds__(256) void k_red0(
    const float* __restrict__ Abuf0, const float* __restrict__ rs0part,
    float* __restrict__ h2raw, float* __restrict__ rowsum)
{
    __shared__ float red[256];
    if (blockIdx.x < 64) {
        int lane = threadIdx.x & 63, w = threadIdx.x >> 6;
        float sum = 0.f;
        for (int ss = blockIdx.x + 64 * w; ss < NN; ss += 256)
            sum += Abuf0[(size_t)ss * EMB + lane];
        red[threadIdx.x] = sum;
        __syncthreads();
        if (threadIdx.x < 64) {
            float v = red[threadIdx.x] + red[threadIdx.x + 64] +
                      red[threadIdx.x + 128] + red[threadIdx.x + 192];
            atomicAdd(&h2raw[threadIdx.x], v);
        }
    } else {
        float sum = 0.f;
        for (int ssp = (int)threadIdx.x; ssp < NN; ssp += 256) sum += rs0part[ssp];
        red[threadIdx.x] = sum;
        __syncthreads();
        for (int off = 128; off > 0; off >>= 1) {
            if (threadIdx.x < off) red[threadIdx.x] += red[threadIdx.x + off];
            __syncthreads();
        }
        if (threadIdx.x == 0) atomicAdd(&rowsum[0], red[0]);
    }
}

// ---------------- E: wave per node n; fused /rowsum + einsum + bias2 ----------------
__global__ __launch_bounds__(1024) void k_logits(
    const float* __restrict__ h2raw, const float* __restrict__ rowsum,
    const float* __restrict__ w2, const float* __restrict__ bias2,
    float* __restrict__ out)
{
    __shared__ float w2s[RP * EMB * NCLS];   // 32 KB
    for (int i = threadIdx.x; i < RP * EMB * NCLS; i += 1024) w2s[i] = w2[i];
    __syncthreads();
    int wv = threadIdx.x >> 6, lane = threadIdx.x & 63;
    int n = blockIdx.x * 16 + wv;            // grid=1250 -> n < 20000 exactly
    int c = lane & 15, es = lane >> 4;
    float acc = 0.f;
#pragma unroll
    for (int r = 0; r < RP; ++r) {
        size_t k = (size_t)r * NN + n;
        float hv = h2raw[k * EMB + lane] / fmaxf(rowsum[k], 1e-6f);
#pragma unroll
        for (int eo = 0; eo < 16; ++eo) {
            float he = __shfl(hv, es * 16 + eo, 64);
            acc = fmaf(he, w2s[(r * EMB + es * 16 + eo) * NCLS + c], acc);
        }
    }
    acc += __shfl_xor(acc, 16, 64);
    acc += __shfl_xor(acc, 32, 64);
    if (lane < 16) out[(size_t)n * NCLS + lane] = acc + bias2[lane];
}

extern "C" void kernel_launch(void* const* d_in, const int* in_sizes, int n_in,
                              void* d_out, int out_size, void* d_ws, size_t ws_size,
                              hipStream_t stream)
{
    const float* rm    = (const float*)d_in[0];
    const int*   hrow  = (const int*)d_in[1];   // sorted source nodes
    const int*   vcol  = (const int*)d_in[4];   // object nodes
    const float* W1    = (const float*)d_in[5];
    const float* b1    = (const float*)d_in[6];
    const float* W2    = (const float*)d_in[7];
    const float* b2    = (const float*)d_in[8];
    const float* w1    = (const float*)d_in[9];
    const float* w2    = (const float*)d_in[10];
    const float* bias1 = (const float*)d_in[11];
    const float* bias2 = (const float*)d_in[12];
    float* out = (float*)d_out;

    float* ws      = (float*)d_ws;
    float* l1T     = ws;                    // 2,000,000
    float* l2T     = ws + 2000000;          // 2,000,000
    float* colsum  = ws + 4000000;          // 160,000
    float* rowsum  = ws + 4160000;          // 160,000
    float* h       = ws + 4320000;          // 1,280,000
    float* h2raw   = ws + 5600000;          // 10,240,000
    int*   rowptr  = (int*)(ws + 15840000); // 20,001 ints
    // Abuf0/rs0part overlay l1T (dead after k_h)
    float* Abuf0   = ws;                    // 1,280,000
    float* rs0part = ws + 1280000;          // 20,000

    hipMemsetAsync(colsum, 0, (size_t)320000 * sizeof(float), stream);   // colsum+rowsum
    hipMemsetAsync(h2raw, 0, (size_t)10240000 * sizeof(float), stream);

    k_rowptr<<<(NN + 256) / 256, 256, 0, stream>>>(hrow, rowptr);
    k_gemv  <<<(NT + GROWS - 1) / GROWS, GROWS, 0, stream>>>(rm, W1, b1, W2, b2, vcol, l1T, l2T, colsum);
    k_h     <<<(NN * 64) / 256, 256, 0, stream>>>(l1T, colsum, rowptr, vcol, w1, bias1, h);
    k_h2    <<<(NN * 64) / 256, 256, 0, stream>>>(l2T, rowptr, vcol, h, h2raw, rowsum, Abuf0, rs0part);
    k_red0  <<<65, 256, 0, stream>>>(Abuf0, rs0part, h2raw, rowsum);
    k_logits<<<NN / 16, 1024, 0, stream>>>(h2raw, rowsum, w2, bias2, out);
}

// Round 4
// 321.193 us; speedup vs baseline: 1.0674x; 1.0674x over previous
//
#include <hip/hip_runtime.h>

#define NT      250000
#define NN      20000
#define RP      8
#define EMB     64
#define NCLS    16
#define NRELS   64
#define COLB    547    // ceil(NN*7/256) work blocks in k_colsum
#define REDB    64     // reducer blocks for colsum[0]

// ---------------- A: per-pair GEMV + softmax (NO atomics) ----------------
__global__ __launch_bounds__(256) void k_gemv(
    const float* __restrict__ rm,
    const float* __restrict__ W1, const float* __restrict__ b1,
    const float* __restrict__ W2, const float* __restrict__ b2,
    float* __restrict__ l1T, float* __restrict__ l2T)
{
    int p = blockIdx.x * blockDim.x + threadIdx.x;
    if (p >= NT) return;
    float a1[RP], a2[RP];
#pragma unroll
    for (int r = 0; r < RP; ++r) { a1[r] = b1[r]; a2[r] = b2[r]; }
    const float4* row = reinterpret_cast<const float4*>(rm + (size_t)p * NRELS);
#pragma unroll 4
    for (int k4 = 0; k4 < NRELS / 4; ++k4) {
        float4 v = row[k4];
        float xs[4] = {v.x, v.y, v.z, v.w};
#pragma unroll
        for (int j = 0; j < 4; ++j) {
            float x = xs[j];
            int k = k4 * 4 + j;
#pragma unroll
            for (int r = 0; r < RP; ++r) {
                a1[r] = fmaf(x, W1[k * RP + r], a1[r]);
                a2[r] = fmaf(x, W2[k * RP + r], a2[r]);
            }
        }
    }
    float m = a2[0];
#pragma unroll
    for (int r = 1; r < RP; ++r) m = fmaxf(m, a2[r]);
    float s = 0.f;
#pragma unroll
    for (int r = 0; r < RP; ++r) { a2[r] = __expf(a2[r] - m); s += a2[r]; }
    float inv = 1.0f / s;
#pragma unroll
    for (int r = 0; r < RP; ++r) a2[r] *= inv;
#pragma unroll
    for (int r = 0; r < RP; ++r) {
        l1T[(size_t)r * NT + p] = a1[r];
        l2T[(size_t)r * NT + p] = a2[r];
    }
}

// ---------------- CSR offsets (hrow sorted by np.unique) ----------------
__global__ __launch_bounds__(256) void k_rowptr(
    const int* __restrict__ hrow, int* __restrict__ rowptr)
{
    int i = blockIdx.x * blockDim.x + threadIdx.x;
    if (i > NN) return;
    int lo = 0, hi = NT;
    while (lo < hi) { int mid = (lo + hi) >> 1; if (hrow[mid] < i) lo = mid + 1; else hi = mid; }
    rowptr[i] = lo;
}

// ---------------- CSC build: histogram of vcol ----------------
__global__ __launch_bounds__(256) void k_hist(
    const int* __restrict__ vcol, int* __restrict__ cnt)
{
    int p = blockIdx.x * blockDim.x + threadIdx.x;
    if (p < NT) atomicAdd(&cnt[vcol[p]], 1);
}

// ---------------- CSC build: single-block exclusive scan of cnt -> cstart, cnt2 ----------------
__global__ __launch_bounds__(1024) void k_scan(
    const int* __restrict__ cnt, int* __restrict__ cstart, int* __restrict__ cnt2)
{
    __shared__ int part[1024];
    int t = threadIdx.x;
    int base = t * 20;
    int local[20];
    int s = 0;
#pragma unroll
    for (int i = 0; i < 20; ++i) {
        int idx = base + i;
        int c = (idx < NN) ? cnt[idx] : 0;
        local[i] = s;
        s += c;
    }
    part[t] = s;
    __syncthreads();
    for (int off = 1; off < 1024; off <<= 1) {
        int v = (t >= off) ? part[t - off] : 0;
        __syncthreads();
        part[t] += v;
        __syncthreads();
    }
    int ebase = t ? part[t - 1] : 0;
#pragma unroll
    for (int i = 0; i < 20; ++i) {
        int idx = base + i;
        if (idx < NN) { cstart[idx] = ebase + local[i]; cnt2[idx] = ebase + local[i]; }
    }
    if (t == 1023) cstart[NN] = part[1023];
}

// ---------------- CSC build: slot assignment ----------------
__global__ __launch_bounds__(256) void k_pos(
    const int* __restrict__ vcol, int* __restrict__ cnt2, int* __restrict__ cscidx)
{
    int p = blockIdx.x * blockDim.x + threadIdx.x;
    if (p >= NT) return;
    int o = vcol[p];
    int slot = atomicAdd(&cnt2[o], 1);
    cscidx[slot] = p;
}

// ---------------- colsum via CSC gather-reduce ----------------
// thread per (o, r=1..7): colsum[o*r] += sum over CSC(o) of l1T[r*NT+p]
// + REDB blocks reduce the r==0 column into colsum[0]
__global__ __launch_bounds__(256) void k_colsum(
    const float* __restrict__ l1T, const int* __restrict__ cstart,
    const int* __restrict__ cscidx, float* __restrict__ colsum)
{
    int bid = blockIdx.x;
    if (bid < COLB) {
        int tid = bid * 256 + threadIdx.x;
        if (tid < NN * 7) {
            int o = tid / 7;
            int r = tid - o * 7 + 1;
            int qb = cstart[o], qe = cstart[o + 1];
            float s = 0.f;
            for (int q = qb; q < qe; ++q)
                s += l1T[(size_t)r * NT + cscidx[q]];
            atomicAdd(&colsum[o * r], s);
        }
    } else {
        int b2 = bid - COLB;
        float s = 0.f;
        for (int i = b2 * 256 + threadIdx.x; i < NT; i += REDB * 256) s += l1T[i];
        __shared__ float red[256];
        red[threadIdx.x] = s;
        __syncthreads();
        for (int off = 128; off > 0; off >>= 1) {
            if (threadIdx.x < off) red[threadIdx.x] += red[threadIdx.x + off];
            __syncthreads();
        }
        if (threadIdx.x == 0) atomicAdd(&colsum[0], red[0]);
    }
}

// ---------------- C: one wave per node s, no atomics ----------------
__global__ __launch_bounds__(256) void k_h(
    const float* __restrict__ l1T, const float* __restrict__ colsum,
    const int* __restrict__ rowptr, const int* __restrict__ vcol,
    const float* __restrict__ w1, const float* __restrict__ bias1,
    float* __restrict__ h)
{
    int wave = (int)((blockIdx.x * blockDim.x + threadIdx.x) >> 6);
    int lane = threadIdx.x & 63;
    if (wave >= NN) return;
    int s = wave;
    int pb = rowptr[s], pe = rowptr[s + 1];
    float acc = 0.f;
    float c0 = 0.f;                      // r==0 factored: seg 0, same w1 row
    for (int p = pb; p < pe; ++p) {
        int o = vcol[p];
        c0 += l1T[p];
#pragma unroll
        for (int r = 1; r < RP; ++r) {
            int seg = o * r;
            float coef = l1T[(size_t)r * NT + p] / colsum[seg];
            acc = fmaf(coef, w1[(size_t)seg * EMB + lane], acc);
        }
    }
    acc = fmaf(c0 / colsum[0], w1[lane], acc);
    h[(size_t)s * EMB + lane] = fmaxf(acc + bias1[lane], 0.f);
}

// ---------------- D: one wave per node s; register-resident 8x64 block ----------------
__global__ __launch_bounds__(256) void k_h2(
    const float* __restrict__ l2T, const int* __restrict__ rowptr,
    const int* __restrict__ vcol, const float* __restrict__ h,
    float* __restrict__ h2raw, float* __restrict__ rowsum,
    float* __restrict__ Abuf0, float* __restrict__ rs0part)
{
    int wave = (int)((blockIdx.x * blockDim.x + threadIdx.x) >> 6);
    int lane = threadIdx.x & 63;
    if (wave >= NN) return;
    int s = wave;
    int pb = rowptr[s], pe = rowptr[s + 1];
    float acc[RP], rs[RP];
#pragma unroll
    for (int r = 0; r < RP; ++r) { acc[r] = 0.f; rs[r] = 0.f; }
    for (int p = pb; p < pe; ++p) {
        int o = vcol[p];
        float hv = h[(size_t)o * EMB + lane];
#pragma unroll
        for (int r = 0; r < RP; ++r) {
            float lv = l2T[(size_t)r * NT + p];
            acc[r] = fmaf(lv, hv, acc[r]);
            rs[r] += lv;
        }
    }
    if (s == 0) {
        float a0 = 0.f, r0 = 0.f;
#pragma unroll
        for (int r = 0; r < RP; ++r) { a0 += acc[r]; r0 += rs[r]; }
        Abuf0[lane] = a0;
        if (lane == 0) rs0part[0] = r0;
    } else {
        Abuf0[(size_t)s * EMB + lane] = acc[0];
        if (lane == 0) rs0part[s] = rs[0];
#pragma unroll
        for (int r = 1; r < RP; ++r) {
            int seg = s * r;
            atomicAdd(&h2raw[(size_t)seg * EMB + lane], acc[r]);
            if (lane == 0) atomicAdd(&rowsum[seg], rs[r]);
        }
    }
}

// ---------------- reduce seg-0 partials ----------------
__global__ __launch_bounds__(256) void k_red0(
    const float* __restrict__ Abuf0, const float* __restrict__ rs0part,
    float* __restrict__ h2raw, float* __restrict__ rowsum)
{
    __shared__ float red[256];
    if (blockIdx.x < 64) {
        int lane = threadIdx.x & 63, w = threadIdx.x >> 6;
        float sum = 0.f;
        for (int ss = blockIdx.x + 64 * w; ss < NN; ss += 256)
            sum += Abuf0[(size_t)ss * EMB + lane];
        red[threadIdx.x] = sum;
        __syncthreads();
        if (threadIdx.x < 64) {
            float v = red[threadIdx.x] + red[threadIdx.x + 64] +
                      red[threadIdx.x + 128] + red[threadIdx.x + 192];
            atomicAdd(&h2raw[threadIdx.x], v);
        }
    } else {
        float sum = 0.f;
        for (int ssp = (int)threadIdx.x; ssp < NN; ssp += 256) sum += rs0part[ssp];
        red[threadIdx.x] = sum;
        __syncthreads();
        for (int off = 128; off > 0; off >>= 1) {
            if (threadIdx.x < off) red[threadIdx.x] += red[threadIdx.x + off];
            __syncthreads();
        }
        if (threadIdx.x == 0) atomicAdd(&rowsum[0], red[0]);
    }
}

// ---------------- E: wave per node n; fused /rowsum + einsum + bias2 ----------------
__global__ __launch_bounds__(1024) void k_logits(
    const float* __restrict__ h2raw, const float* __restrict__ rowsum,
    const float* __restrict__ w2, const float* __restrict__ bias2,
    float* __restrict__ out)
{
    __shared__ float w2s[RP * EMB * NCLS];   // 32 KB
    for (int i = threadIdx.x; i < RP * EMB * NCLS; i += 1024) w2s[i] = w2[i];
    __syncthreads();
    int wv = threadIdx.x >> 6, lane = threadIdx.x & 63;
    int n = blockIdx.x * 16 + wv;            // grid=1250 -> n < 20000 exactly
    int c = lane & 15, es = lane >> 4;
    float acc = 0.f;
#pragma unroll
    for (int r = 0; r < RP; ++r) {
        size_t k = (size_t)r * NN + n;
        float hv = h2raw[k * EMB + lane] / fmaxf(rowsum[k], 1e-6f);
#pragma unroll
        for (int eo = 0; eo < 16; ++eo) {
            float he = __shfl(hv, es * 16 + eo, 64);
            acc = fmaf(he, w2s[(r * EMB + es * 16 + eo) * NCLS + c], acc);
        }
    }
    acc += __shfl_xor(acc, 16, 64);
    acc += __shfl_xor(acc, 32, 64);
    if (lane < 16) out[(size_t)n * NCLS + lane] = acc + bias2[lane];
}

extern "C" void kernel_launch(void* const* d_in, const int* in_sizes, int n_in,
                              void* d_out, int out_size, void* d_ws, size_t ws_size,
                              hipStream_t stream)
{
    const float* rm    = (const float*)d_in[0];
    const int*   hrow  = (const int*)d_in[1];   // sorted source nodes
    const int*   vcol  = (const int*)d_in[4];   // object nodes
    const float* W1    = (const float*)d_in[5];
    const float* b1    = (const float*)d_in[6];
    const float* W2    = (const float*)d_in[7];
    const float* b2    = (const float*)d_in[8];
    const float* w1    = (const float*)d_in[9];
    const float* w2    = (const float*)d_in[10];
    const float* bias1 = (const float*)d_in[11];
    const float* bias2 = (const float*)d_in[12];
    float* out = (float*)d_out;

    float* ws      = (float*)d_ws;
    float* l1T     = ws;                    // 2,000,000
    float* l2T     = ws + 2000000;          // 2,000,000
    float* colsum  = ws + 4000000;          // 160,000
    float* rowsum  = ws + 4160000;          // 160,000
    float* h       = ws + 4320000;          // 1,280,000 (written by k_h)
    float* h2raw   = ws + 5600000;          // 10,240,000
    int*   rowptr  = (int*)(ws + 15840000); // 20,001 ints
    // CSC scratch aliases the h region (dead until k_h, which runs after k_colsum)
    int* cnt    = (int*)(ws + 4320000);     // 20,000
    int* cstart = cnt + 20000;              // 20,001
    int* cnt2   = cstart + 20001;           // 20,000
    int* cscidx = cnt2 + 20000;             // 250,000  (total 1.24 MB < h's 5.12 MB)
    // Abuf0/rs0part overlay l1T (dead after k_h)
    float* Abuf0   = ws;                    // 1,280,000
    float* rs0part = ws + 1280000;          // 20,000

    hipMemsetAsync(colsum, 0, (size_t)320000 * sizeof(float), stream);   // colsum+rowsum
    hipMemsetAsync(h2raw, 0, (size_t)10240000 * sizeof(float), stream);
    hipMemsetAsync(cnt, 0, (size_t)20000 * sizeof(int), stream);

    k_rowptr<<<(NN + 256) / 256, 256, 0, stream>>>(hrow, rowptr);
    k_hist  <<<(NT + 255) / 256, 256, 0, stream>>>(vcol, cnt);
    k_scan  <<<1, 1024, 0, stream>>>(cnt, cstart, cnt2);
    k_pos   <<<(NT + 255) / 256, 256, 0, stream>>>(vcol, cnt2, cscidx);
    k_gemv  <<<(NT + 255) / 256, 256, 0, stream>>>(rm, W1, b1, W2, b2, l1T, l2T);
    k_colsum<<<COLB + REDB, 256, 0, stream>>>(l1T, cstart, cscidx, colsum);
    k_h     <<<(NN * 64) / 256, 256, 0, stream>>>(l1T, colsum, rowptr, vcol, w1, bias1, h);
    k_h2    <<<(NN * 64) / 256, 256, 0, stream>>>(l2T, rowptr, vcol, h, h2raw, rowsum, Abuf0, rs0part);
    k_red0  <<<65, 256, 0, stream>>>(Abuf0, rs0part, h2raw, rowsum);
    k_logits<<<NN / 16, 1024, 0, stream>>>(h2raw, rowsum, w2, bias2, out);
}